// Round 5
// baseline (145.996 us; speedup 1.0000x reference)
//
#include <hip/hip_runtime.h>

#define NROWS 8192
#define HALF_N 4096
#define DIM 512
#define INV_T 10.0f
#define NRB 64              // number of 128-row blocks
#define NBLOCKS 2080        // 64*65/2 upper-triangle block pairs

typedef __attribute__((ext_vector_type(8))) short short8;
typedef __attribute__((ext_vector_type(4))) float f32x4;

__device__ __forceinline__ ushort f32_to_bf16_rne(float x) {
  unsigned u = __float_as_uint(x);
  unsigned r = (u + 0x7fffu + ((u >> 16) & 1u)) >> 16;
  return (ushort)r;
}

__device__ __forceinline__ void async16(const void* g, void* l) {
  __builtin_amdgcn_global_load_lds(
      (const __attribute__((address_space(1))) unsigned int*)g,
      (__attribute__((address_space(3))) unsigned int*)l, 16, 0, 0);
}

// Kernel 1: L2-normalize rows of [f1;f2] -> bf16 Fn; zero rowsum + counter.
__global__ __launch_bounds__(256) void norm_cast_k(
    const float* __restrict__ f1, const float* __restrict__ f2,
    ushort* __restrict__ Fn, float* __restrict__ rowsum,
    unsigned* __restrict__ cnt) {
  int wave = threadIdx.x >> 6;
  int lane = threadIdx.x & 63;
  int row = blockIdx.x * 4 + wave;
  const float* src = (row < HALF_N) ? (f1 + (size_t)row * DIM)
                                    : (f2 + (size_t)(row - HALF_N) * DIM);
  const float4* p = reinterpret_cast<const float4*>(src + lane * 8);
  float4 v0 = p[0];
  float4 v1 = p[1];
  float ss = v0.x*v0.x + v0.y*v0.y + v0.z*v0.z + v0.w*v0.w
           + v1.x*v1.x + v1.y*v1.y + v1.z*v1.z + v1.w*v1.w;
  #pragma unroll
  for (int off = 1; off < 64; off <<= 1) ss += __shfl_xor(ss, off);
  float scale = 1.0f / fmaxf(sqrtf(ss), 1e-12f);
  union { ushort u[8]; short8 v; } o;
  o.u[0] = f32_to_bf16_rne(v0.x * scale);
  o.u[1] = f32_to_bf16_rne(v0.y * scale);
  o.u[2] = f32_to_bf16_rne(v0.z * scale);
  o.u[3] = f32_to_bf16_rne(v0.w * scale);
  o.u[4] = f32_to_bf16_rne(v1.x * scale);
  o.u[5] = f32_to_bf16_rne(v1.y * scale);
  o.u[6] = f32_to_bf16_rne(v1.z * scale);
  o.u[7] = f32_to_bf16_rne(v1.w * scale);
  *reinterpret_cast<short8*>(Fn + (size_t)row * DIM + lane * 8) = o.v;
  if (lane == 0) rowsum[row] = 0.0f;
  if (blockIdx.x == 0 && threadIdx.x == 0) *cnt = 0u;
}

// Kernel 2: symmetric upper-triangle sim GEMM + fused exp accumulation +
// last-block loss finalize. R2 structure (BK=32, single-buffer, proven
// conflict-free swizzle) with occupancy raised to 4 blocks/CU.
__global__ __launch_bounds__(256, 4) void sym_gemm_k(
    const ushort* __restrict__ Fn, float* __restrict__ rowsum,
    float* __restrict__ pairsim, unsigned* __restrict__ cnt,
    float* __restrict__ out) {
  // XCD-contiguous remap of the triangle index
  int bx = blockIdx.x;
  int gbx = (bx & 7) * (NBLOCKS / 8) + (bx >> 3);
  int rb = 0, rem = gbx;
  while (rem >= NRB - rb) { rem -= NRB - rb; ++rb; }
  const int cb = rb + rem;
  const int row0 = rb * 128, col0 = cb * 128;

  const int tid = threadIdx.x;
  const int wave = tid >> 6;
  const int lane = tid & 63;
  const int quad = lane >> 4;
  const int colid = lane & 15;
  const int wr0 = (wave >> 1) * 64;
  const int wc0 = (wave & 1) * 64;

  // LDS tiles: 128 rows x 32 k bf16 = 64 B/row, 4 x 16B chunks per row.
  // Physical chunk = logical ^ ((row>>1)&3) -> conflict-free frag reads.
  __shared__ ushort Alds[128 * 32];
  __shared__ ushort Blds[128 * 32];
  __shared__ float redrow[128];
  __shared__ float redcol[128];
  __shared__ float fred[4];
  __shared__ unsigned lastflag;

  if (tid < 128) { redrow[tid] = 0.0f; redcol[tid] = 0.0f; }

  // ---- staging addresses ----
  // 16 insts/round: wave w owns A insts {w, w+4}, B insts {w, w+4};
  // inst i covers rows [i*16, i*16+16): lane -> r = i*16 + (lane>>2),
  // phys chunk = lane&3, logical chunk = (lane&3) ^ ((r>>1)&3).
  const char* FnB = (const char*)Fn;
  const char* srcA[2]; const char* srcB[2];
  ushort* dstA[2]; ushort* dstB[2];
  #pragma unroll
  for (int seg = 0; seg < 2; ++seg) {
    int inst = wave + seg * 4;
    int r = inst * 16 + (lane >> 2);
    int c = (lane & 3) ^ ((r >> 1) & 3);
    srcA[seg] = FnB + (size_t)(row0 + r) * (DIM * 2) + c * 16;
    srcB[seg] = FnB + (size_t)(col0 + r) * (DIM * 2) + c * 16;
    dstA[seg] = Alds + inst * 512;   // 1 KB per inst
    dstB[seg] = Blds + inst * 512;
  }

  // ---- fragment LDS pointers (constant across rounds) ----
  // A operand (16x16x32): lane holds A[m = colid][k = quad*8 + j].
  const ushort* afp[4]; const ushort* bfp[4];
  #pragma unroll
  for (int t = 0; t < 4; ++t) {
    int ra = wr0 + t * 16 + colid;
    afp[t] = Alds + ra * 32 + ((quad ^ ((ra >> 1) & 3)) << 3);
    int rc = wc0 + t * 16 + colid;
    bfp[t] = Blds + rc * 32 + ((quad ^ ((rc >> 1) & 3)) << 3);
  }

  f32x4 acc[4][4];
  #pragma unroll
  for (int t = 0; t < 4; ++t)
    #pragma unroll
    for (int u = 0; u < 4; ++u) acc[t][u] = (f32x4){0.f, 0.f, 0.f, 0.f};

  for (int kc = 0; kc < 16; ++kc) {
    __syncthreads();                   // prior round's reads done
    const size_t ko = (size_t)kc * 64; // 32 k-elems = 64 B per row
    #pragma unroll
    for (int seg = 0; seg < 2; ++seg) {
      async16(srcA[seg] + ko, dstA[seg]);
      async16(srcB[seg] + ko, dstB[seg]);
    }
    __syncthreads();                   // drains DMA -> tiles visible

    short8 af[4], bfr[4];
    #pragma unroll
    for (int t = 0; t < 4; ++t) af[t] = *reinterpret_cast<const short8*>(afp[t]);
    #pragma unroll
    for (int u = 0; u < 4; ++u) bfr[u] = *reinterpret_cast<const short8*>(bfp[u]);
    #pragma unroll
    for (int t = 0; t < 4; ++t)
      #pragma unroll
      for (int u = 0; u < 4; ++u)
        acc[t][u] = __builtin_amdgcn_mfma_f32_16x16x32_bf16(af[t], bfr[u], acc[t][u], 0, 0, 0);
  }

  // ---- epilogue: exp + row/col accumulation ----
  // C/D layout: col = lane&15, row = quad*4 + reg (m89-verified).
  float re[4][4];
  float ce[4];
  #pragma unroll
  for (int t = 0; t < 4; ++t)
    #pragma unroll
    for (int r = 0; r < 4; ++r) re[t][r] = 0.0f;
  #pragma unroll
  for (int u = 0; u < 4; ++u) ce[u] = 0.0f;

  #pragma unroll
  for (int t = 0; t < 4; ++t) {
    #pragma unroll
    for (int u = 0; u < 4; ++u) {
      f32x4 a = acc[t][u];
      const int gc = col0 + wc0 + u * 16 + colid;
      #pragma unroll
      for (int r = 0; r < 4; ++r) {
        int grow = row0 + wr0 + t * 16 + quad * 4 + r;
        float sim = a[r] * INV_T;
        float e = (gc > grow) ? __expf(sim) : 0.0f;  // strict upper triangle
        re[t][r] += e;
        ce[u] += e;
        if (gc == grow + HALF_N && grow < HALF_N) {
          atomicExch(&pairsim[grow], sim);   // device-coherent store
          atomicExch(&pairsim[gc], sim);
        }
      }
    }
  }

  #pragma unroll
  for (int t = 0; t < 4; ++t)
    #pragma unroll
    for (int r = 0; r < 4; ++r) {
      float v = re[t][r];
      v += __shfl_xor(v, 1); v += __shfl_xor(v, 2);
      v += __shfl_xor(v, 4); v += __shfl_xor(v, 8);
      if (colid == 0) atomicAdd(&redrow[wr0 + t * 16 + quad * 4 + r], v);
    }
  #pragma unroll
  for (int u = 0; u < 4; ++u) {
    float v = ce[u];
    v += __shfl_xor(v, 16); v += __shfl_xor(v, 32);
    if (lane < 16) atomicAdd(&redcol[wc0 + u * 16 + colid], v);
  }
  __syncthreads();
  if (tid < 128) atomicAdd(&rowsum[row0 + tid], redrow[tid]);
  else           atomicAdd(&rowsum[col0 + tid - 128], redcol[tid - 128]);
  __syncthreads();   // all block atomics issued before cnt bump

  // ---- last-block loss finalize (no producer-side fence!) ----
  if (tid == 0)
    lastflag = (atomicAdd(cnt, 1u) == NBLOCKS - 1) ? 1u : 0u;
  __syncthreads();
  if (lastflag) {
    __threadfence();   // acquire side only (runs in ONE block)
    float local = 0.0f;
    for (int i = tid; i < NROWS; i += 256) {
      float rs = __hip_atomic_load(&rowsum[i], __ATOMIC_RELAXED,
                                   __HIP_MEMORY_SCOPE_AGENT);
      float ps = __hip_atomic_load(&pairsim[i], __ATOMIC_RELAXED,
                                   __HIP_MEMORY_SCOPE_AGENT);
      local += __logf(rs) - ps;
    }
    #pragma unroll
    for (int off = 1; off < 64; off <<= 1) local += __shfl_xor(local, off);
    if (lane == 0) fred[wave] = local;
    __syncthreads();
    if (tid == 0)
      out[0] = (fred[0] + fred[1] + fred[2] + fred[3]) * (1.0f / (float)NROWS);
  }
}

extern "C" void kernel_launch(void* const* d_in, const int* in_sizes, int n_in,
                              void* d_out, int out_size, void* d_ws, size_t ws_size,
                              hipStream_t stream) {
  const float* f1 = (const float*)d_in[0];
  const float* f2 = (const float*)d_in[1];
  ushort* Fn = (ushort*)d_ws;                                   // 8 MB bf16
  float* rowsum = (float*)((char*)d_ws + (size_t)NROWS * DIM * 2);
  float* pairsim = rowsum + NROWS;
  unsigned* cnt = (unsigned*)(pairsim + NROWS);
  float* out = (float*)d_out;

  norm_cast_k<<<NROWS / 4, 256, 0, stream>>>(f1, f2, Fn, rowsum, cnt);
  sym_gemm_k<<<NBLOCKS, 256, 0, stream>>>(Fn, rowsum, pairsim, cnt, out);
}

// Round 6
// 125.367 us; speedup vs baseline: 1.1645x; 1.1645x over previous
//
#include <hip/hip_runtime.h>

#define NROWS 8192
#define HALF_N 4096
#define DIM 512
#define INV_T 10.0f
#define NRB 64              // number of 128-row blocks
#define NBLOCKS 2080        // 64*65/2 upper-triangle block pairs

typedef __attribute__((ext_vector_type(8))) short short8;
typedef __attribute__((ext_vector_type(4))) float f32x4;

__device__ __forceinline__ ushort f32_to_bf16_rne(float x) {
  unsigned u = __float_as_uint(x);
  unsigned r = (u + 0x7fffu + ((u >> 16) & 1u)) >> 16;
  return (ushort)r;
}

// async 16B global -> LDS (DMA, no VGPR round trip). LDS dest is
// wave-uniform base + lane*16; global src is per-lane.
__device__ __forceinline__ void async16(const void* g, void* l) {
  __builtin_amdgcn_global_load_lds(
      (const __attribute__((address_space(1))) unsigned int*)g,
      (__attribute__((address_space(3))) unsigned int*)l, 16, 0, 0);
}

// Kernel 1: L2-normalize rows of [f1;f2] -> bf16 Fn; zero rowsum.
// 256 threads = 4 waves, one row per wave.
__global__ __launch_bounds__(256) void norm_cast_k(
    const float* __restrict__ f1, const float* __restrict__ f2,
    ushort* __restrict__ Fn, float* __restrict__ rowsum) {
  int wave = threadIdx.x >> 6;
  int lane = threadIdx.x & 63;
  int row = blockIdx.x * 4 + wave;
  const float* src = (row < HALF_N) ? (f1 + (size_t)row * DIM)
                                    : (f2 + (size_t)(row - HALF_N) * DIM);
  const float4* p = reinterpret_cast<const float4*>(src + lane * 8);
  float4 v0 = p[0];
  float4 v1 = p[1];
  float ss = v0.x*v0.x + v0.y*v0.y + v0.z*v0.z + v0.w*v0.w
           + v1.x*v1.x + v1.y*v1.y + v1.z*v1.z + v1.w*v1.w;
  #pragma unroll
  for (int off = 1; off < 64; off <<= 1) ss += __shfl_xor(ss, off);
  float scale = 1.0f / fmaxf(sqrtf(ss), 1e-12f);
  union { ushort u[8]; short8 v; } o;
  o.u[0] = f32_to_bf16_rne(v0.x * scale);
  o.u[1] = f32_to_bf16_rne(v0.y * scale);
  o.u[2] = f32_to_bf16_rne(v0.z * scale);
  o.u[3] = f32_to_bf16_rne(v0.w * scale);
  o.u[4] = f32_to_bf16_rne(v1.x * scale);
  o.u[5] = f32_to_bf16_rne(v1.y * scale);
  o.u[6] = f32_to_bf16_rne(v1.z * scale);
  o.u[7] = f32_to_bf16_rne(v1.w * scale);
  *reinterpret_cast<short8*>(Fn + (size_t)row * DIM + lane * 8) = o.v;
  if (lane == 0) rowsum[row] = 0.0f;
}

// Kernel 2: symmetric upper-triangle sim GEMM, fused exp row+col accumulation.
// Grid: 2080 blocks = (rb, cb) with cb >= rb, 128x128 output tiles.
// m97 structure: K streamed in BK=32 rounds, A/B tiles (8 KB each) staged via
// global_load_lds, 4 waves each computing a 64x64 register tile.
__global__ __launch_bounds__(256, 3) void sym_gemm_k(
    const ushort* __restrict__ Fn, float* __restrict__ rowsum,
    float* __restrict__ pairsim) {
  // XCD-contiguous remap: each XCD (bx%8) gets a contiguous 260-block range
  int bx = blockIdx.x;
  int gbx = (bx & 7) * (NBLOCKS / 8) + (bx >> 3);
  int rb = 0, rem = gbx;
  while (rem >= NRB - rb) { rem -= NRB - rb; ++rb; }
  const int cb = rb + rem;
  const int row0 = rb * 128, col0 = cb * 128;

  const int tid = threadIdx.x;
  const int wave = tid >> 6;
  const int lane = tid & 63;
  const int quad = lane >> 4;
  const int colid = lane & 15;
  const int wr0 = (wave >> 1) * 64;   // wave's row offset within tile
  const int wc0 = (wave & 1) * 64;    // wave's col offset within tile

  // LDS tiles: 128 rows x 32 k bf16 = 64 B/row, 4 x 16B chunks per row.
  // Physical chunk = logical ^ ((row>>1)&3)  -> conflict-free frag reads.
  __shared__ ushort Alds[128 * 32];
  __shared__ ushort Blds[128 * 32];
  __shared__ float redrow[128];
  __shared__ float redcol[128];

  if (tid < 128) { redrow[tid] = 0.0f; redcol[tid] = 0.0f; }

  // Staging: 16 x 1KB wave-instructions per round (8 A + 8 B), wave w owns
  // A insts {w, w+4} and B insts {w, w+4}. Inst i covers rows [i*16, i*16+16).
  // lane -> local row r = i*16 + (lane>>2), physical chunk p = lane&3;
  // global source uses logical chunk c = p ^ ((r>>1)&3) (swizzle inverse).
  const char* FnB = (const char*)Fn;
  const char* srcA[2]; const char* srcB[2];
  ushort* dstA[2]; ushort* dstB[2];
  #pragma unroll
  for (int seg = 0; seg < 2; ++seg) {
    int inst = wave + seg * 4;
    int r = inst * 16 + (lane >> 2);
    int c = (lane & 3) ^ ((r >> 1) & 3);
    srcA[seg] = FnB + (size_t)(row0 + r) * (DIM * 2) + c * 16;
    srcB[seg] = FnB + (size_t)(col0 + r) * (DIM * 2) + c * 16;
    dstA[seg] = Alds + inst * 512;   // 1 KB per inst
    dstB[seg] = Blds + inst * 512;
  }

  // Fragment LDS addresses (constant across rounds).
  // A operand (16x16x32): lane holds A[m = lane&15][k = quad*8 + j].
  const ushort* afp[4]; const ushort* bfp[4];
  #pragma unroll
  for (int t = 0; t < 4; ++t) {
    int r = wr0 + t * 16 + colid;
    afp[t] = Alds + r * 32 + ((quad ^ ((r >> 1) & 3)) << 3);
    int c = wc0 + t * 16 + colid;
    bfp[t] = Blds + c * 32 + ((quad ^ ((c >> 1) & 3)) << 3);
  }

  f32x4 acc[4][4];
  #pragma unroll
  for (int t = 0; t < 4; ++t)
    #pragma unroll
    for (int u = 0; u < 4; ++u) acc[t][u] = (f32x4){0.f, 0.f, 0.f, 0.f};

  for (int kc = 0; kc < 16; ++kc) {
    __syncthreads();                   // prior round's reads done
    const size_t ko = (size_t)kc * 64; // 32 k-elems = 64 B per row
    #pragma unroll
    for (int seg = 0; seg < 2; ++seg) {
      async16(srcA[seg] + ko, dstA[seg]);
      async16(srcB[seg] + ko, dstB[seg]);
    }
    __syncthreads();                   // drains DMA -> tiles visible

    short8 af[4], bf[4];
    #pragma unroll
    for (int t = 0; t < 4; ++t) af[t] = *reinterpret_cast<const short8*>(afp[t]);
    #pragma unroll
    for (int u = 0; u < 4; ++u) bf[u] = *reinterpret_cast<const short8*>(bfp[u]);
    #pragma unroll
    for (int t = 0; t < 4; ++t)
      #pragma unroll
      for (int u = 0; u < 4; ++u)
        acc[t][u] = __builtin_amdgcn_mfma_f32_16x16x32_bf16(af[t], bf[u], acc[t][u], 0, 0, 0);
  }

  // Epilogue. C/D layout: col = lane&15, row = quad*4 + reg (m89-verified).
  float re[4][4];                      // per (t, reg): sum over ct + this col
  float ce[4];                         // per ct: sum over t,reg for this col
  #pragma unroll
  for (int t = 0; t < 4; ++t)
    #pragma unroll
    for (int r = 0; r < 4; ++r) re[t][r] = 0.0f;
  #pragma unroll
  for (int u = 0; u < 4; ++u) ce[u] = 0.0f;

  #pragma unroll
  for (int t = 0; t < 4; ++t) {
    #pragma unroll
    for (int u = 0; u < 4; ++u) {
      f32x4 a = acc[t][u];
      const int gc = col0 + wc0 + u * 16 + colid;
      #pragma unroll
      for (int r = 0; r < 4; ++r) {
        int grow = row0 + wr0 + t * 16 + quad * 4 + r;
        float sim = a[r] * INV_T;
        float e = (gc > grow) ? __expf(sim) : 0.0f;  // strict upper triangle
        re[t][r] += e;
        ce[u] += e;
        if (gc == grow + HALF_N && grow < HALF_N) {
          pairsim[grow] = sim;         // unique writer per pair
          pairsim[gc] = sim;
        }
      }
    }
  }

  // Row sums: reduce across the 16 col-lanes, LDS-accumulate.
  #pragma unroll
  for (int t = 0; t < 4; ++t)
    #pragma unroll
    for (int r = 0; r < 4; ++r) {
      float v = re[t][r];
      v += __shfl_xor(v, 1); v += __shfl_xor(v, 2);
      v += __shfl_xor(v, 4); v += __shfl_xor(v, 8);
      if (colid == 0) atomicAdd(&redrow[wr0 + t * 16 + quad * 4 + r], v);
    }
  // Col sums: reduce across the 4 quads (this wave's 64 rows).
  #pragma unroll
  for (int u = 0; u < 4; ++u) {
    float v = ce[u];
    v += __shfl_xor(v, 16); v += __shfl_xor(v, 32);
    if (lane < 16) atomicAdd(&redcol[wc0 + u * 16 + colid], v);
  }
  __syncthreads();
  if (tid < 128) atomicAdd(&rowsum[row0 + tid], redrow[tid]);
  else           atomicAdd(&rowsum[col0 + tid - 128], redcol[tid - 128]);
}

// Kernel 3: loss = mean_i( log(rowsum_i) - pairsim_i ). Single block.
__global__ __launch_bounds__(1024) void finalize_k(
    const float* __restrict__ rowsum, const float* __restrict__ pairsim,
    float* __restrict__ out) {
  float local = 0.0f;
  for (int i = threadIdx.x; i < NROWS; i += 1024)
    local += logf(rowsum[i]) - pairsim[i];
  #pragma unroll
  for (int off = 1; off < 64; off <<= 1) local += __shfl_xor(local, off);
  __shared__ float red[16];
  int wave = threadIdx.x >> 6;
  int lane = threadIdx.x & 63;
  if (lane == 0) red[wave] = local;
  __syncthreads();
  if (threadIdx.x == 0) {
    float s = 0.0f;
    #pragma unroll
    for (int w = 0; w < 16; ++w) s += red[w];
    out[0] = s * (1.0f / (float)NROWS);
  }
}

extern "C" void kernel_launch(void* const* d_in, const int* in_sizes, int n_in,
                              void* d_out, int out_size, void* d_ws, size_t ws_size,
                              hipStream_t stream) {
  const float* f1 = (const float*)d_in[0];
  const float* f2 = (const float*)d_in[1];
  ushort* Fn = (ushort*)d_ws;                                   // 8 MB bf16
  float* rowsum = (float*)((char*)d_ws + (size_t)NROWS * DIM * 2);
  float* pairsim = rowsum + NROWS;
  float* out = (float*)d_out;

  norm_cast_k<<<NROWS / 4, 256, 0, stream>>>(f1, f2, Fn, rowsum);
  sym_gemm_k<<<NBLOCKS, 256, 0, stream>>>(Fn, rowsum, pairsim);
  finalize_k<<<1, 1024, 0, stream>>>(rowsum, pairsim, out);
}

// Round 7
// 111.246 us; speedup vs baseline: 1.3124x; 1.1269x over previous
//
#include <hip/hip_runtime.h>

#define NROWS 8192
#define HALF_N 4096
#define DIM 512
#define INV_T 10.0f
#define NRB 64              // number of 128-row blocks
#define NBLOCKS 2080        // 64*65/2 upper-triangle block pairs

typedef __attribute__((ext_vector_type(4))) float f32x4;

// async 16B global -> LDS (DMA, no VGPR round trip). LDS dest is
// wave-uniform base + lane*16; global src is per-lane.
__device__ __forceinline__ void async16(const void* g, void* l) {
  __builtin_amdgcn_global_load_lds(
      (const __attribute__((address_space(1))) unsigned int*)g,
      (__attribute__((address_space(3))) unsigned int*)l, 16, 0, 0);
}

// Kernel 1: L2-normalize rows of [f1;f2] -> fp8 e4m3 Fn; zero rowsum.
// 256 threads = 4 waves, one row per wave. One int2 (8 fp8) store per lane.
__global__ __launch_bounds__(256) void norm_cast_k(
    const float* __restrict__ f1, const float* __restrict__ f2,
    unsigned char* __restrict__ Fn, float* __restrict__ rowsum) {
  int wave = threadIdx.x >> 6;
  int lane = threadIdx.x & 63;
  int row = blockIdx.x * 4 + wave;
  const float* src = (row < HALF_N) ? (f1 + (size_t)row * DIM)
                                    : (f2 + (size_t)(row - HALF_N) * DIM);
  const float4* p = reinterpret_cast<const float4*>(src + lane * 8);
  float4 v0 = p[0];
  float4 v1 = p[1];
  float ss = v0.x*v0.x + v0.y*v0.y + v0.z*v0.z + v0.w*v0.w
           + v1.x*v1.x + v1.y*v1.y + v1.z*v1.z + v1.w*v1.w;
  #pragma unroll
  for (int off = 1; off < 64; off <<= 1) ss += __shfl_xor(ss, off);
  float scale = 1.0f / fmaxf(sqrtf(ss), 1e-12f);
  // pack 8 consecutive coords into 8 fp8 e4m3 bytes (v_cvt_pk_fp8_f32)
  int lo = __builtin_amdgcn_cvt_pk_fp8_f32(v0.x * scale, v0.y * scale, 0, false);
  lo = __builtin_amdgcn_cvt_pk_fp8_f32(v0.z * scale, v0.w * scale, lo, true);
  int hi = __builtin_amdgcn_cvt_pk_fp8_f32(v1.x * scale, v1.y * scale, 0, false);
  hi = __builtin_amdgcn_cvt_pk_fp8_f32(v1.z * scale, v1.w * scale, hi, true);
  *reinterpret_cast<int2*>(Fn + (size_t)row * DIM + lane * 8) = make_int2(lo, hi);
  if (lane == 0) rowsum[row] = 0.0f;
}

// Kernel 2: symmetric upper-triangle sim GEMM (fp8 e4m3 inputs), fused exp
// row+col accumulation. 128x128 tiles, BK=64 (8 rounds), A/B staged via
// global_load_lds (16 x 1KB insts/round, same geometry as the proven bf16
// BK=32 version), 4 waves x (64x64) register tiles.
__global__ __launch_bounds__(256, 3) void sym_gemm_k(
    const unsigned char* __restrict__ Fn, float* __restrict__ rowsum,
    float* __restrict__ pairsim) {
  // XCD-contiguous remap: each XCD (bx%8) gets a contiguous 260-block range
  int bx = blockIdx.x;
  int gbx = (bx & 7) * (NBLOCKS / 8) + (bx >> 3);
  int rb = 0, rem = gbx;
  while (rem >= NRB - rb) { rem -= NRB - rb; ++rb; }
  const int cb = rb + rem;
  const int row0 = rb * 128, col0 = cb * 128;

  const int tid = threadIdx.x;
  const int wave = tid >> 6;
  const int lane = tid & 63;
  const int quad = lane >> 4;
  const int colid = lane & 15;
  const int wr0 = (wave >> 1) * 64;   // wave's row offset within tile
  const int wc0 = (wave & 1) * 64;    // wave's col offset within tile

  // LDS tiles: 128 rows x 64 k fp8 = 64 B/row, 4 x 16B chunks per row.
  // Physical 16B chunk = logical ^ ((row>>1)&3) -> <=2-way (free) b64 reads.
  __shared__ __align__(16) unsigned char Alds[128 * 64];
  __shared__ __align__(16) unsigned char Blds[128 * 64];
  __shared__ float redrow[128];
  __shared__ float redcol[128];

  if (tid < 128) { redrow[tid] = 0.0f; redcol[tid] = 0.0f; }

  // Staging: 16 x 1KB wave-instructions per round (8 A + 8 B), wave w owns
  // A insts {w, w+4} and B insts {w, w+4}. Inst i covers rows [i*16, i*16+16).
  // lane -> local row r = i*16 + (lane>>2), physical chunk p = lane&3;
  // global source uses logical chunk c = p ^ ((r>>1)&3) (swizzle inverse).
  const unsigned char* srcA[2]; const unsigned char* srcB[2];
  unsigned char* dstA[2]; unsigned char* dstB[2];
  #pragma unroll
  for (int seg = 0; seg < 2; ++seg) {
    int inst = wave + seg * 4;
    int r = inst * 16 + (lane >> 2);
    int c = (lane & 3) ^ ((r >> 1) & 3);
    srcA[seg] = Fn + (size_t)(row0 + r) * DIM + c * 16;
    srcB[seg] = Fn + (size_t)(col0 + r) * DIM + c * 16;
    dstA[seg] = Alds + inst * 1024;   // 16 rows x 64 B per inst
    dstB[seg] = Blds + inst * 1024;
  }

  // Fragment LDS addresses (constant across rounds).
  // fp8 16x16x32 A operand: lane holds A[m = colid][k = quad*8 + j], 8 bytes.
  // s in {0,1} selects the K=32 half of the 64-elem row: logical 8B unit
  // u8 = s*4 + quad -> 16B chunk c16 = s*2 + (quad>>1), half = quad&1.
  const unsigned char* afp[4][2]; const unsigned char* bfp[4][2];
  #pragma unroll
  for (int t = 0; t < 4; ++t) {
    int ra = wr0 + t * 16 + colid;
    int rc = wc0 + t * 16 + colid;
    #pragma unroll
    for (int s = 0; s < 2; ++s) {
      int c16 = s * 2 + (quad >> 1);
      afp[t][s] = Alds + ra * 64 + ((c16 ^ ((ra >> 1) & 3)) << 4) + (quad & 1) * 8;
      bfp[t][s] = Blds + rc * 64 + ((c16 ^ ((rc >> 1) & 3)) << 4) + (quad & 1) * 8;
    }
  }

  f32x4 acc[4][4];
  #pragma unroll
  for (int t = 0; t < 4; ++t)
    #pragma unroll
    for (int u = 0; u < 4; ++u) acc[t][u] = (f32x4){0.f, 0.f, 0.f, 0.f};

  for (int kc = 0; kc < 8; ++kc) {
    __syncthreads();                   // prior round's reads done
    const size_t ko = (size_t)kc * 64; // 64 k-elems = 64 B per row
    #pragma unroll
    for (int seg = 0; seg < 2; ++seg) {
      async16(srcA[seg] + ko, dstA[seg]);
      async16(srcB[seg] + ko, dstB[seg]);
    }
    __syncthreads();                   // drains DMA -> tiles visible

    #pragma unroll
    for (int s = 0; s < 2; ++s) {
      long af[4], bf[4];
      #pragma unroll
      for (int t = 0; t < 4; ++t) af[t] = *reinterpret_cast<const long*>(afp[t][s]);
      #pragma unroll
      for (int u = 0; u < 4; ++u) bf[u] = *reinterpret_cast<const long*>(bfp[u][s]);
      #pragma unroll
      for (int t = 0; t < 4; ++t)
        #pragma unroll
        for (int u = 0; u < 4; ++u)
          acc[t][u] = __builtin_amdgcn_mfma_f32_16x16x32_fp8_fp8(af[t], bf[u], acc[t][u], 0, 0, 0);
    }
  }

  // Epilogue. C/D layout: col = lane&15, row = quad*4 + reg (m89-verified,
  // dtype-independent on gfx950).
  float re[4][4];                      // per (t, reg) row-sum contribution
  float ce[4];                         // per ct col-sum contribution
  #pragma unroll
  for (int t = 0; t < 4; ++t)
    #pragma unroll
    for (int r = 0; r < 4; ++r) re[t][r] = 0.0f;
  #pragma unroll
  for (int u = 0; u < 4; ++u) ce[u] = 0.0f;

  #pragma unroll
  for (int t = 0; t < 4; ++t) {
    #pragma unroll
    for (int u = 0; u < 4; ++u) {
      f32x4 a = acc[t][u];
      const int gc = col0 + wc0 + u * 16 + colid;
      #pragma unroll
      for (int r = 0; r < 4; ++r) {
        int grow = row0 + wr0 + t * 16 + quad * 4 + r;
        float sim = a[r] * INV_T;
        float e = (gc > grow) ? __expf(sim) : 0.0f;  // strict upper triangle
        re[t][r] += e;
        ce[u] += e;
        if (gc == grow + HALF_N && grow < HALF_N) {
          pairsim[grow] = sim;         // unique writer per pair
          pairsim[gc] = sim;
        }
      }
    }
  }

  // Row sums: reduce across the 16 col-lanes, LDS-accumulate.
  #pragma unroll
  for (int t = 0; t < 4; ++t)
    #pragma unroll
    for (int r = 0; r < 4; ++r) {
      float v = re[t][r];
      v += __shfl_xor(v, 1); v += __shfl_xor(v, 2);
      v += __shfl_xor(v, 4); v += __shfl_xor(v, 8);
      if (colid == 0) atomicAdd(&redrow[wr0 + t * 16 + quad * 4 + r], v);
    }
  // Col sums: reduce across the 4 quads (this wave's 64 rows).
  #pragma unroll
  for (int u = 0; u < 4; ++u) {
    float v = ce[u];
    v += __shfl_xor(v, 16); v += __shfl_xor(v, 32);
    if (lane < 16) atomicAdd(&redcol[wc0 + u * 16 + colid], v);
  }
  __syncthreads();
  if (tid < 128) atomicAdd(&rowsum[row0 + tid], redrow[tid]);
  else           atomicAdd(&rowsum[col0 + tid - 128], redcol[tid - 128]);
}

// Kernel 3: loss = mean_i( log(rowsum_i) - pairsim_i ). Single block.
__global__ __launch_bounds__(1024) void finalize_k(
    const float* __restrict__ rowsum, const float* __restrict__ pairsim,
    float* __restrict__ out) {
  float local = 0.0f;
  for (int i = threadIdx.x; i < NROWS; i += 1024)
    local += logf(rowsum[i]) - pairsim[i];
  #pragma unroll
  for (int off = 1; off < 64; off <<= 1) local += __shfl_xor(local, off);
  __shared__ float red[16];
  int wave = threadIdx.x >> 6;
  int lane = threadIdx.x & 63;
  if (lane == 0) red[wave] = local;
  __syncthreads();
  if (threadIdx.x == 0) {
    float s = 0.0f;
    #pragma unroll
    for (int w = 0; w < 16; ++w) s += red[w];
    out[0] = s * (1.0f / (float)NROWS);
  }
}

extern "C" void kernel_launch(void* const* d_in, const int* in_sizes, int n_in,
                              void* d_out, int out_size, void* d_ws, size_t ws_size,
                              hipStream_t stream) {
  const float* f1 = (const float*)d_in[0];
  const float* f2 = (const float*)d_in[1];
  unsigned char* Fn = (unsigned char*)d_ws;                     // 4 MB fp8
  float* rowsum = (float*)((char*)d_ws + (size_t)NROWS * DIM);
  float* pairsim = rowsum + NROWS;
  float* out = (float*)d_out;

  norm_cast_k<<<NROWS / 4, 256, 0, stream>>>(f1, f2, Fn, rowsum);
  sym_gemm_k<<<NBLOCKS, 256, 0, stream>>>(Fn, rowsum, pairsim);
  finalize_k<<<1, 1024, 0, stream>>>(rowsum, pairsim, out);
}

// Round 8
// 104.837 us; speedup vs baseline: 1.3926x; 1.0611x over previous
//
#include <hip/hip_runtime.h>

#define NROWS 8192
#define HALF_N 4096
#define DIM 512
#define INV_T 10.0f
#define NRB 64              // number of 128-row blocks
#define NBLOCKS 2080        // 64*65/2 upper-triangle block pairs

typedef __attribute__((ext_vector_type(4))) float f32x4;
typedef __attribute__((ext_vector_type(2))) long long2v;

// async 16B global -> LDS (DMA, no VGPR round trip). LDS dest is
// wave-uniform base + lane*16; global src is per-lane.
__device__ __forceinline__ void async16(const void* g, void* l) {
  __builtin_amdgcn_global_load_lds(
      (const __attribute__((address_space(1))) unsigned int*)g,
      (__attribute__((address_space(3))) unsigned int*)l, 16, 0, 0);
}

// Kernel 1: L2-normalize rows of [f1;f2] -> fp8 e4m3 Fn; zero rowsum.
// K-PERMUTED layout: within each 64-byte k-group, 8B unit u is stored at
// position p = 2*(u&3) + (u>>2). (A and B share the permutation, so the
// GEMM result is unchanged; it makes each lane's two K=32 fragments
// adjacent -> single ds_read_b128 in the GEMM.)
__global__ __launch_bounds__(256) void norm_cast_k(
    const float* __restrict__ f1, const float* __restrict__ f2,
    unsigned char* __restrict__ Fn, float* __restrict__ rowsum) {
  int wave = threadIdx.x >> 6;
  int lane = threadIdx.x & 63;
  int row = blockIdx.x * 4 + wave;
  const float* src = (row < HALF_N) ? (f1 + (size_t)row * DIM)
                                    : (f2 + (size_t)(row - HALF_N) * DIM);
  const float4* p = reinterpret_cast<const float4*>(src + lane * 8);
  float4 v0 = p[0];
  float4 v1 = p[1];
  float ss = v0.x*v0.x + v0.y*v0.y + v0.z*v0.z + v0.w*v0.w
           + v1.x*v1.x + v1.y*v1.y + v1.z*v1.z + v1.w*v1.w;
  #pragma unroll
  for (int off = 1; off < 64; off <<= 1) ss += __shfl_xor(ss, off);
  float scale = 1.0f / fmaxf(sqrtf(ss), 1e-12f);
  // pack 8 consecutive coords into 8 fp8 e4m3 bytes (v_cvt_pk_fp8_f32)
  int lo = __builtin_amdgcn_cvt_pk_fp8_f32(v0.x * scale, v0.y * scale, 0, false);
  lo = __builtin_amdgcn_cvt_pk_fp8_f32(v0.z * scale, v0.w * scale, lo, true);
  // lane's 8 coords = k-unit u = lane&7 of k-group g = lane>>3
  int u = lane & 7;
  int g = lane >> 3;
  int pos = 2 * (u & 3) + (u >> 2);          // permuted unit position
  *reinterpret_cast<int2*>(Fn + (size_t)row * DIM + g * 64 + pos * 8) =
      make_int2(lo,
                __builtin_amdgcn_cvt_pk_fp8_f32(v1.z * scale, v1.w * scale,
                    __builtin_amdgcn_cvt_pk_fp8_f32(v1.x * scale, v1.y * scale, 0, false),
                    true));
  if (lane == 0) rowsum[row] = 0.0f;
}

// Kernel 2: symmetric upper-triangle sim GEMM (fp8 e4m3, k-permuted), fused
// exp row+col accumulation. 128x128 tiles, BK=64 (8 rounds), staging via
// global_load_lds (16 x 1KB insts/round), 4 waves x (64x64) register tiles.
// Fragment reads are ds_read_b128 with the R2-proven conflict-free swizzle.
__global__ __launch_bounds__(256, 3) void sym_gemm_k(
    const unsigned char* __restrict__ Fn, float* __restrict__ rowsum,
    float* __restrict__ pairsim) {
  // XCD-contiguous remap: each XCD (bx%8) gets a contiguous 260-block range
  int bx = blockIdx.x;
  int gbx = (bx & 7) * (NBLOCKS / 8) + (bx >> 3);
  int rb = 0, rem = gbx;
  while (rem >= NRB - rb) { rem -= NRB - rb; ++rb; }
  const int cb = rb + rem;
  const int row0 = rb * 128, col0 = cb * 128;

  const int tid = threadIdx.x;
  const int wave = tid >> 6;
  const int lane = tid & 63;
  const int quad = lane >> 4;
  const int colid = lane & 15;
  const int wr0 = (wave >> 1) * 64;   // wave's row offset within tile
  const int wc0 = (wave & 1) * 64;    // wave's col offset within tile

  // LDS tiles: 128 rows x 64 k fp8 = 64 B/row, 4 x 16B chunks per row.
  // Physical 16B chunk = logical ^ ((row>>1)&3) -> conflict-free b128 reads
  // (same geometry as the bf16 R2 kernel that measured 0 conflicts).
  __shared__ __align__(16) unsigned char Alds[128 * 64];
  __shared__ __align__(16) unsigned char Blds[128 * 64];
  __shared__ float redrow[128];
  __shared__ float redcol[128];

  if (tid < 128) { redrow[tid] = 0.0f; redcol[tid] = 0.0f; }

  // Staging: 16 x 1KB wave-instructions per round (8 A + 8 B), wave w owns
  // A insts {w, w+4} and B insts {w, w+4}. Inst i covers rows [i*16, i*16+16).
  // lane -> local row r = i*16 + (lane>>2), physical chunk p = lane&3;
  // global source uses logical chunk c = p ^ ((r>>1)&3) (swizzle inverse).
  const unsigned char* srcA[2]; const unsigned char* srcB[2];
  unsigned char* dstA[2]; unsigned char* dstB[2];
  #pragma unroll
  for (int seg = 0; seg < 2; ++seg) {
    int inst = wave + seg * 4;
    int r = inst * 16 + (lane >> 2);
    int c = (lane & 3) ^ ((r >> 1) & 3);
    srcA[seg] = Fn + (size_t)(row0 + r) * DIM + c * 16;
    srcB[seg] = Fn + (size_t)(col0 + r) * DIM + c * 16;
    dstA[seg] = Alds + inst * 1024;   // 16 rows x 64 B per inst
    dstB[seg] = Blds + inst * 1024;
  }

  // Fragment LDS addresses (constant across rounds): ONE b128 per row-tile.
  // Logical chunk = quad (holds units {s=0,s=1} for this quad, k-permuted);
  // physical = quad ^ ((row>>1)&3).
  const unsigned char* afp[4]; const unsigned char* bfp[4];
  #pragma unroll
  for (int t = 0; t < 4; ++t) {
    int ra = wr0 + t * 16 + colid;
    int rc = wc0 + t * 16 + colid;
    afp[t] = Alds + ra * 64 + ((quad ^ ((ra >> 1) & 3)) << 4);
    bfp[t] = Blds + rc * 64 + ((quad ^ ((rc >> 1) & 3)) << 4);
  }

  f32x4 acc[4][4];
  #pragma unroll
  for (int t = 0; t < 4; ++t)
    #pragma unroll
    for (int u = 0; u < 4; ++u) acc[t][u] = (f32x4){0.f, 0.f, 0.f, 0.f};

  for (int kc = 0; kc < 8; ++kc) {
    __syncthreads();                   // prior round's reads done
    const size_t ko = (size_t)kc * 64; // 64 k-elems = 64 B per row
    #pragma unroll
    for (int seg = 0; seg < 2; ++seg) {
      async16(srcA[seg] + ko, dstA[seg]);
      async16(srcB[seg] + ko, dstB[seg]);
    }
    __syncthreads();                   // drains DMA -> tiles visible

    long2v af[4], bf[4];
    #pragma unroll
    for (int t = 0; t < 4; ++t) af[t] = *reinterpret_cast<const long2v*>(afp[t]);
    #pragma unroll
    for (int u = 0; u < 4; ++u) bf[u] = *reinterpret_cast<const long2v*>(bfp[u]);
    #pragma unroll
    for (int s = 0; s < 2; ++s)
      #pragma unroll
      for (int t = 0; t < 4; ++t)
        #pragma unroll
        for (int u = 0; u < 4; ++u)
          acc[t][u] = __builtin_amdgcn_mfma_f32_16x16x32_fp8_fp8(
              af[t][s], bf[u][s], acc[t][u], 0, 0, 0);
  }

  // Epilogue. C/D layout: col = lane&15, row = quad*4 + reg (m89-verified,
  // dtype-independent on gfx950).
  float re[4][4];
  float ce[4];
  #pragma unroll
  for (int t = 0; t < 4; ++t)
    #pragma unroll
    for (int r = 0; r < 4; ++r) re[t][r] = 0.0f;
  #pragma unroll
  for (int u = 0; u < 4; ++u) ce[u] = 0.0f;

  #pragma unroll
  for (int t = 0; t < 4; ++t) {
    #pragma unroll
    for (int u = 0; u < 4; ++u) {
      f32x4 a = acc[t][u];
      const int gc = col0 + wc0 + u * 16 + colid;
      #pragma unroll
      for (int r = 0; r < 4; ++r) {
        int grow = row0 + wr0 + t * 16 + quad * 4 + r;
        float sim = a[r] * INV_T;
        float e = (gc > grow) ? __expf(sim) : 0.0f;  // strict upper triangle
        re[t][r] += e;
        ce[u] += e;
        if (gc == grow + HALF_N && grow < HALF_N) {
          pairsim[grow] = sim;         // unique writer per pair
          pairsim[gc] = sim;
        }
      }
    }
  }

  // Row sums: reduce across the 16 col-lanes, LDS-accumulate.
  #pragma unroll
  for (int t = 0; t < 4; ++t)
    #pragma unroll
    for (int r = 0; r < 4; ++r) {
      float v = re[t][r];
      v += __shfl_xor(v, 1); v += __shfl_xor(v, 2);
      v += __shfl_xor(v, 4); v += __shfl_xor(v, 8);
      if (colid == 0) atomicAdd(&redrow[wr0 + t * 16 + quad * 4 + r], v);
    }
  // Col sums: reduce across the 4 quads (this wave's 64 rows).
  #pragma unroll
  for (int u = 0; u < 4; ++u) {
    float v = ce[u];
    v += __shfl_xor(v, 16); v += __shfl_xor(v, 32);
    if (lane < 16) atomicAdd(&redcol[wc0 + u * 16 + colid], v);
  }
  __syncthreads();
  if (tid < 128) atomicAdd(&rowsum[row0 + tid], redrow[tid]);
  else           atomicAdd(&rowsum[col0 + tid - 128], redcol[tid - 128]);
}

// Kernel 3: loss = mean_i( log(rowsum_i) - pairsim_i ). Single block.
__global__ __launch_bounds__(1024) void finalize_k(
    const float* __restrict__ rowsum, const float* __restrict__ pairsim,
    float* __restrict__ out) {
  float local = 0.0f;
  for (int i = threadIdx.x; i < NROWS; i += 1024)
    local += logf(rowsum[i]) - pairsim[i];
  #pragma unroll
  for (int off = 1; off < 64; off <<= 1) local += __shfl_xor(local, off);
  __shared__ float red[16];
  int wave = threadIdx.x >> 6;
  int lane = threadIdx.x & 63;
  if (lane == 0) red[wave] = local;
  __syncthreads();
  if (threadIdx.x == 0) {
    float s = 0.0f;
    #pragma unroll
    for (int w = 0; w < 16; ++w) s += red[w];
    out[0] = s * (1.0f / (float)NROWS);
  }
}

extern "C" void kernel_launch(void* const* d_in, const int* in_sizes, int n_in,
                              void* d_out, int out_size, void* d_ws, size_t ws_size,
                              hipStream_t stream) {
  const float* f1 = (const float*)d_in[0];
  const float* f2 = (const float*)d_in[1];
  unsigned char* Fn = (unsigned char*)d_ws;                     // 4 MB fp8
  float* rowsum = (float*)((char*)d_ws + (size_t)NROWS * DIM);
  float* pairsim = rowsum + NROWS;
  float* out = (float*)d_out;

  norm_cast_k<<<NROWS / 4, 256, 0, stream>>>(f1, f2, Fn, rowsum);
  sym_gemm_k<<<NBLOCKS, 256, 0, stream>>>(Fn, rowsum, pairsim);
  finalize_k<<<1, 1024, 0, stream>>>(rowsum, pairsim, out);
}